// Round 1
// baseline (1942.602 us; speedup 1.0000x reference)
//
#include <hip/hip_runtime.h>
#include <hip/hip_bf16.h>

typedef __attribute__((ext_vector_type(4))) float  f32x4;
typedef __attribute__((ext_vector_type(8))) short  bf16x8;
typedef __attribute__((ext_vector_type(4))) int    i32x4;

#define M_DIM 8192
#define N_DIM 11008
#define K_DIM 4096
#define KP    2048          // packed int32 per weight row (K/2)
#define BK    64
#define NKT   (K_DIM / BK)  // 64 K-steps

// LDS byte address with XOR swizzle: row-major [128][64] bf16 tiles (128 B rows),
// swizzle spreads the per-row 16B slots across banks (8 lanes/slot = data-path min).
__device__ __forceinline__ int swz(int row, int kbyte) {
    return row * 128 + (kbyte ^ ((row & 7) << 4));
}

__device__ __forceinline__ short f2bf(float f) {
    return __builtin_bit_cast(short, __float2bfloat16(f));
}

__global__ __launch_bounds__(256, 2)
void qlin_kernel(const float* __restrict__ x,
                 const int*   __restrict__ wq,
                 const float* __restrict__ scale,
                 const float* __restrict__ bias,
                 float* __restrict__ out)
{
    __shared__ short As[128 * 64];   // [m][k] bf16, swizzled
    __shared__ short Bs[128 * 64];   // [n][k] bf16 (B^T layout), swizzled

    const int t  = threadIdx.x;
    const int n0 = blockIdx.x * 128;
    const int m0 = blockIdx.y * 128;

    // ---- staging roles: 2 threads per row, each covers 32 k ----
    const int sr = t >> 1;      // tile row 0..127
    const int sh = t & 1;       // k-half 0/1

    const float* ag = x  + (size_t)(m0 + sr) * K_DIM + sh * 32;
    const int*   bg = wq + (size_t)(n0 + sr) * KP    + sh * 16;

    // ---- compute roles ----
    const int lane = t & 63;
    const int wv   = t >> 6;    // wave 0..3
    const int wm   = wv >> 1;   // 0..1 -> rows [wm*64, +64)
    const int wn   = wv & 1;    // 0..1 -> cols [wn*64, +64)
    const int lr   = lane & 15; // fragment row/col within 16
    const int lk   = lane >> 4; // k-group 0..3 (8 contiguous bf16 each)

    f32x4 acc[4][4];
    #pragma unroll
    for (int i = 0; i < 4; ++i)
        #pragma unroll
        for (int j = 0; j < 4; ++j)
            acc[i][j] = (f32x4){0.f, 0.f, 0.f, 0.f};

    f32x4 ar[8];   // 32 floats of A per thread
    i32x4 br[4];   // 16 packed ints (32 int4) of W per thread

    // prologue: load tile 0
    #pragma unroll
    for (int i = 0; i < 8; ++i) ar[i] = *(const f32x4*)(ag + i * 4);
    #pragma unroll
    for (int i = 0; i < 4; ++i) br[i] = *(const i32x4*)(bg + i * 4);

    for (int kt = 0; kt < NKT; ++kt) {
        // ---- convert staged regs -> LDS ----
        #pragma unroll
        for (int c = 0; c < 4; ++c) {
            bf16x8 pa;
            #pragma unroll
            for (int j = 0; j < 8; ++j)
                pa[j] = f2bf(ar[c * 2 + (j >> 2)][j & 3]);
            *(bf16x8*)((char*)As + swz(sr, sh * 64 + c * 16)) = pa;

            bf16x8 pb;
            #pragma unroll
            for (int j = 0; j < 4; ++j) {
                const int q = br[c][j] ^ 0x88;   // xor both nibbles with 8
                // (nib^8) in [0,15]; magic-or into fp32 mantissa, subtract 2^23+8
                const float flo = __builtin_bit_cast(float, 0x4B000000 | (q & 15))        - 8388616.0f;
                const float fhi = __builtin_bit_cast(float, 0x4B000000 | ((q >> 4) & 15)) - 8388616.0f;
                pb[2 * j]     = f2bf(flo);   // even k = low nibble
                pb[2 * j + 1] = f2bf(fhi);   // odd  k = high nibble
            }
            *(bf16x8*)((char*)Bs + swz(sr, sh * 64 + c * 16)) = pb;
        }
        __syncthreads();

        // ---- prefetch next tile into regs (in flight during MFMA) ----
        if (kt + 1 < NKT) {
            const float* an = ag + (kt + 1) * BK;
            const int*   bn = bg + (kt + 1) * (BK / 2);
            #pragma unroll
            for (int i = 0; i < 8; ++i) ar[i] = *(const f32x4*)(an + i * 4);
            #pragma unroll
            for (int i = 0; i < 4; ++i) br[i] = *(const i32x4*)(bn + i * 4);
        }

        // ---- MFMA on current tile ----
        #pragma unroll
        for (int ks = 0; ks < 2; ++ks) {
            const int kb = ks * 64 + lk * 16;
            bf16x8 af[4], bfr[4];
            #pragma unroll
            for (int mi = 0; mi < 4; ++mi)
                af[mi] = *(const bf16x8*)((const char*)As + swz(wm * 64 + mi * 16 + lr, kb));
            #pragma unroll
            for (int ni = 0; ni < 4; ++ni)
                bfr[ni] = *(const bf16x8*)((const char*)Bs + swz(wn * 64 + ni * 16 + lr, kb));
            #pragma unroll
            for (int mi = 0; mi < 4; ++mi)
                #pragma unroll
                for (int ni = 0; ni < 4; ++ni)
                    acc[mi][ni] = __builtin_amdgcn_mfma_f32_16x16x32_bf16(
                        af[mi], bfr[ni], acc[mi][ni], 0, 0, 0);
        }
        __syncthreads();
    }

    // ---- epilogue: out = acc * scale[n] + bias[n] ----
    // C/D layout (verified m89/m91): col = lane&15, row = (lane>>4)*4 + reg
    #pragma unroll
    for (int ni = 0; ni < 4; ++ni) {
        const int gn = n0 + wn * 64 + ni * 16 + lr;
        const float sc = scale[gn];
        const float bi = bias[gn];
        #pragma unroll
        for (int mi = 0; mi < 4; ++mi) {
            const int gm = m0 + wm * 64 + mi * 16 + lk * 4;
            const f32x4 v = acc[mi][ni];
            #pragma unroll
            for (int r2 = 0; r2 < 4; ++r2)
                out[(size_t)(gm + r2) * N_DIM + gn] = v[r2] * sc + bi;
        }
    }
}

extern "C" void kernel_launch(void* const* d_in, const int* in_sizes, int n_in,
                              void* d_out, int out_size, void* d_ws, size_t ws_size,
                              hipStream_t stream)
{
    const float* x     = (const float*)d_in[0];
    const int*   wq    = (const int*)d_in[1];
    const float* scale = (const float*)d_in[2];
    const float* bias  = (const float*)d_in[3];
    float*       out   = (float*)d_out;

    dim3 grid(N_DIM / 128, M_DIM / 128);  // 86 x 64
    qlin_kernel<<<grid, 256, 0, stream>>>(x, wq, scale, bias, out);
}

// Round 2
// 1214.921 us; speedup vs baseline: 1.5990x; 1.5990x over previous
//
#include <hip/hip_runtime.h>
#include <hip/hip_bf16.h>

typedef __attribute__((ext_vector_type(4))) float  f32x4;
typedef __attribute__((ext_vector_type(8))) short  bf16x8;
typedef __attribute__((ext_vector_type(4))) int    i32x4;

#define M_DIM 8192
#define N_DIM 11008
#define K_DIM 4096
#define KP    2048          // packed int32 per weight row (K/2)
#define BK    64
#define NKT   (K_DIM / BK)  // 64 K-steps

#define A_WS_BYTES ((size_t)M_DIM * K_DIM * 2)   // 67,108,864
#define B_WS_BYTES ((size_t)N_DIM * K_DIM * 2)   // 90,177,536
#define WS_NEED    (A_WS_BYTES + B_WS_BYTES)     // 157,286,400

__device__ __forceinline__ short f2bf(float f) {
    return __builtin_bit_cast(short, __float2bfloat16(f));
}

// ---------------- prepass: x fp32 -> bf16 ----------------
__global__ __launch_bounds__(256)
void cvt_x_kernel(const float* __restrict__ x, short* __restrict__ xb)
{
    const size_t i = ((size_t)blockIdx.x * 256 + threadIdx.x) * 8;
    const f32x4 a = *(const f32x4*)(x + i);
    const f32x4 b = *(const f32x4*)(x + i + 4);
    bf16x8 o;
    #pragma unroll
    for (int j = 0; j < 4; ++j) {
        o[j]     = f2bf(a[j]);
        o[4 + j] = f2bf(b[j]);
    }
    *(bf16x8*)(xb + i) = o;
}

// ---------------- prepass: packed int4 -> bf16 (exact small ints) ----------------
__global__ __launch_bounds__(256)
void dequant_w_kernel(const int* __restrict__ wq, short* __restrict__ wb)
{
    const size_t i = ((size_t)blockIdx.x * 256 + threadIdx.x) * 4;
    const i32x4 v = *(const i32x4*)(wq + i);
    bf16x8 o;
    #pragma unroll
    for (int j = 0; j < 4; ++j) {
        const int q = (v[j] & 0xFF) ^ 0x88;            // xor both nibbles with 8
        o[2 * j]     = f2bf((float)((q & 15) - 8));    // even k = low nibble
        o[2 * j + 1] = f2bf((float)(((q >> 4) & 15) - 8)); // odd k = high nibble
    }
    *(bf16x8*)(wb + i * 2) = o;
}

// ---------------- main GEMM: m97 structure, global_load_lds width=16 ----------------
__global__ __launch_bounds__(256)
void gemm_kernel(const short* __restrict__ A,     // [8192][4096] bf16
                 const short* __restrict__ Bw,    // [11008][4096] bf16 (B^T layout)
                 const float* __restrict__ scale,
                 const float* __restrict__ bias,
                 float* __restrict__ out)
{
    __shared__ short As[128 * 64];   // [m][k], linear (global_load_lds needs linear dest)
    __shared__ short Bs[128 * 64];   // [n][k], linear

    const int t    = threadIdx.x;
    const int lane = t & 63;
    const int wv   = t >> 6;        // wave 0..3
    const int n0   = blockIdx.x * 128;
    const int m0   = blockIdx.y * 128;

    const int wm = wv >> 1;         // wave row 0..1
    const int wn = wv & 1;          // wave col 0..1
    const int lr = lane & 15;       // fragment row/col
    const int lk = lane >> 4;       // k-group

    // staging: chunk c = wv*4+r covers 8 rows (1024 B); lane covers row c*8+(l>>3), 16 B slot l&7
    const int srow = lane >> 3;
    const int skb  = (lane & 7) * 16;

    f32x4 acc[4][4];
    #pragma unroll
    for (int i = 0; i < 4; ++i)
        #pragma unroll
        for (int j = 0; j < 4; ++j)
            acc[i][j] = (f32x4){0.f, 0.f, 0.f, 0.f};

    const char* Abase = (const char*)A  + (size_t)m0 * K_DIM * 2;
    const char* Bbase = (const char*)Bw + (size_t)n0 * K_DIM * 2;

    for (int kt = 0; kt < NKT; ++kt) {
        const size_t koff = (size_t)kt * BK * 2;   // 128 B per row segment
        #pragma unroll
        for (int r = 0; r < 4; ++r) {
            const int c   = wv * 4 + r;
            const int row = c * 8 + srow;
            __builtin_amdgcn_global_load_lds(
                (const __attribute__((address_space(1))) unsigned int*)
                    (Abase + (size_t)row * (K_DIM * 2) + koff + skb),
                (__attribute__((address_space(3))) unsigned int*)((char*)As + c * 1024),
                16, 0, 0);
            __builtin_amdgcn_global_load_lds(
                (const __attribute__((address_space(1))) unsigned int*)
                    (Bbase + (size_t)row * (K_DIM * 2) + koff + skb),
                (__attribute__((address_space(3))) unsigned int*)((char*)Bs + c * 1024),
                16, 0, 0);
        }
        __syncthreads();   // drains vmcnt(0) -> tiles ready

        #pragma unroll
        for (int ks = 0; ks < 2; ++ks) {
            const int kb = ks * 64 + lk * 16;   // byte offset within 128-B row
            bf16x8 af[4], bfr[4];
            #pragma unroll
            for (int mi = 0; mi < 4; ++mi)
                af[mi] = *(const bf16x8*)((const char*)As + (wm * 64 + mi * 16 + lr) * 128 + kb);
            #pragma unroll
            for (int ni = 0; ni < 4; ++ni)
                bfr[ni] = *(const bf16x8*)((const char*)Bs + (wn * 64 + ni * 16 + lr) * 128 + kb);
            #pragma unroll
            for (int mi = 0; mi < 4; ++mi)
                #pragma unroll
                for (int ni = 0; ni < 4; ++ni)
                    acc[mi][ni] = __builtin_amdgcn_mfma_f32_16x16x32_bf16(
                        af[mi], bfr[ni], acc[mi][ni], 0, 0, 0);
        }
        __syncthreads();
    }

    // epilogue: out = acc * scale[n] + bias[n]
    // C/D layout (verified m89/m91): col = lane&15, row = (lane>>4)*4 + reg
    #pragma unroll
    for (int ni = 0; ni < 4; ++ni) {
        const int gn = n0 + wn * 64 + ni * 16 + lr;
        const float sc = scale[gn];
        const float bi = bias[gn];
        #pragma unroll
        for (int mi = 0; mi < 4; ++mi) {
            const int gm = m0 + wm * 64 + mi * 16 + lk * 4;
            const f32x4 v = acc[mi][ni];
            #pragma unroll
            for (int r2 = 0; r2 < 4; ++r2)
                out[(size_t)(gm + r2) * N_DIM + gn] = v[r2] * sc + bi;
        }
    }
}

// ---------------- fallback: fused dequant GEMM (R1 kernel, known-good) ----------------
__device__ __forceinline__ int swz(int row, int kbyte) {
    return row * 128 + (kbyte ^ ((row & 7) << 4));
}

__global__ __launch_bounds__(256, 2)
void qlin_kernel(const float* __restrict__ x,
                 const int*   __restrict__ wq,
                 const float* __restrict__ scale,
                 const float* __restrict__ bias,
                 float* __restrict__ out)
{
    __shared__ short As[128 * 64];
    __shared__ short Bs[128 * 64];

    const int t  = threadIdx.x;
    const int n0 = blockIdx.x * 128;
    const int m0 = blockIdx.y * 128;

    const int sr = t >> 1;
    const int sh = t & 1;

    const float* ag = x  + (size_t)(m0 + sr) * K_DIM + sh * 32;
    const int*   bg = wq + (size_t)(n0 + sr) * KP    + sh * 16;

    const int lane = t & 63;
    const int wv   = t >> 6;
    const int wm   = wv >> 1;
    const int wn   = wv & 1;
    const int lr   = lane & 15;
    const int lk   = lane >> 4;

    f32x4 acc[4][4];
    #pragma unroll
    for (int i = 0; i < 4; ++i)
        #pragma unroll
        for (int j = 0; j < 4; ++j)
            acc[i][j] = (f32x4){0.f, 0.f, 0.f, 0.f};

    f32x4 ar[8];
    i32x4 br[4];

    #pragma unroll
    for (int i = 0; i < 8; ++i) ar[i] = *(const f32x4*)(ag + i * 4);
    #pragma unroll
    for (int i = 0; i < 4; ++i) br[i] = *(const i32x4*)(bg + i * 4);

    for (int kt = 0; kt < NKT; ++kt) {
        #pragma unroll
        for (int c = 0; c < 4; ++c) {
            bf16x8 pa;
            #pragma unroll
            for (int j = 0; j < 8; ++j)
                pa[j] = f2bf(ar[c * 2 + (j >> 2)][j & 3]);
            *(bf16x8*)((char*)As + swz(sr, sh * 64 + c * 16)) = pa;

            bf16x8 pb;
            #pragma unroll
            for (int j = 0; j < 4; ++j) {
                const int q = br[c][j] ^ 0x88;
                const float flo = __builtin_bit_cast(float, 0x4B000000 | (q & 15))        - 8388616.0f;
                const float fhi = __builtin_bit_cast(float, 0x4B000000 | ((q >> 4) & 15)) - 8388616.0f;
                pb[2 * j]     = f2bf(flo);
                pb[2 * j + 1] = f2bf(fhi);
            }
            *(bf16x8*)((char*)Bs + swz(sr, sh * 64 + c * 16)) = pb;
        }
        __syncthreads();

        if (kt + 1 < NKT) {
            const float* an = ag + (kt + 1) * BK;
            const int*   bn = bg + (kt + 1) * (BK / 2);
            #pragma unroll
            for (int i = 0; i < 8; ++i) ar[i] = *(const f32x4*)(an + i * 4);
            #pragma unroll
            for (int i = 0; i < 4; ++i) br[i] = *(const i32x4*)(bn + i * 4);
        }

        #pragma unroll
        for (int ks = 0; ks < 2; ++ks) {
            const int kb = ks * 64 + lk * 16;
            bf16x8 af[4], bfr[4];
            #pragma unroll
            for (int mi = 0; mi < 4; ++mi)
                af[mi] = *(const bf16x8*)((const char*)As + swz(wm * 64 + mi * 16 + lr, kb));
            #pragma unroll
            for (int ni = 0; ni < 4; ++ni)
                bfr[ni] = *(const bf16x8*)((const char*)Bs + swz(wn * 64 + ni * 16 + lr, kb));
            #pragma unroll
            for (int mi = 0; mi < 4; ++mi)
                #pragma unroll
                for (int ni = 0; ni < 4; ++ni)
                    acc[mi][ni] = __builtin_amdgcn_mfma_f32_16x16x32_bf16(
                        af[mi], bfr[ni], acc[mi][ni], 0, 0, 0);
        }
        __syncthreads();
    }

    #pragma unroll
    for (int ni = 0; ni < 4; ++ni) {
        const int gn = n0 + wn * 64 + ni * 16 + lr;
        const float sc = scale[gn];
        const float bi = bias[gn];
        #pragma unroll
        for (int mi = 0; mi < 4; ++mi) {
            const int gm = m0 + wm * 64 + mi * 16 + lk * 4;
            const f32x4 v = acc[mi][ni];
            #pragma unroll
            for (int r2 = 0; r2 < 4; ++r2)
                out[(size_t)(gm + r2) * N_DIM + gn] = v[r2] * sc + bi;
        }
    }
}

extern "C" void kernel_launch(void* const* d_in, const int* in_sizes, int n_in,
                              void* d_out, int out_size, void* d_ws, size_t ws_size,
                              hipStream_t stream)
{
    const float* x     = (const float*)d_in[0];
    const int*   wq    = (const int*)d_in[1];
    const float* scale = (const float*)d_in[2];
    const float* bias  = (const float*)d_in[3];
    float*       out   = (float*)d_out;

    if (ws_size >= WS_NEED) {
        short* xb = (short*)d_ws;
        short* wb = (short*)((char*)d_ws + A_WS_BYTES);
        // prepass: 8192*4096/8/256 = 16384 blocks; 11008*2048/4/256 = 22016 blocks
        cvt_x_kernel<<<16384, 256, 0, stream>>>(x, xb);
        dequant_w_kernel<<<22016, 256, 0, stream>>>(wq, wb);
        gemm_kernel<<<dim3(N_DIM / 128, M_DIM / 128), 256, 0, stream>>>(xb, wb, scale, bias, out);
    } else {
        qlin_kernel<<<dim3(N_DIM / 128, M_DIM / 128), 256, 0, stream>>>(x, wq, scale, bias, out);
    }
}

// Round 3
// 810.945 us; speedup vs baseline: 2.3955x; 1.4982x over previous
//
#include <hip/hip_runtime.h>
#include <hip/hip_bf16.h>

typedef __attribute__((ext_vector_type(4))) float  f32x4;
typedef __attribute__((ext_vector_type(8))) short  bf16x8;
typedef __attribute__((ext_vector_type(4))) int    i32x4;

#define M_DIM 8192
#define N_DIM 11008
#define K_DIM 4096
#define KP    2048

#define A_WS_BYTES ((size_t)M_DIM * K_DIM * 2)
#define B_WS_BYTES ((size_t)N_DIM * K_DIM * 2)
#define WS_NEED    (A_WS_BYTES + B_WS_BYTES)

// 256x256 tile, 8 waves (2M x 4N), BK=32, 4-deep LDS pipeline
#define BM 256
#define BN 256
#define BK 32
#define NT (K_DIM / BK)              // 128 K-tiles
#define NBUF 4
#define TILE_A_BYTES (BM * BK * 2)   // 16384
#define BUF_BYTES    (2 * TILE_A_BYTES) // 32768 (A then B)

__device__ __forceinline__ short f2bf(float f) {
    return __builtin_bit_cast(short, __float2bfloat16(f));
}

// ---------------- prepass: x fp32 -> bf16 ----------------
__global__ __launch_bounds__(256)
void cvt_x_kernel(const float* __restrict__ x, short* __restrict__ xb)
{
    const size_t i = ((size_t)blockIdx.x * 256 + threadIdx.x) * 8;
    const f32x4 a = *(const f32x4*)(x + i);
    const f32x4 b = *(const f32x4*)(x + i + 4);
    bf16x8 o;
    #pragma unroll
    for (int j = 0; j < 4; ++j) {
        o[j]     = f2bf(a[j]);
        o[4 + j] = f2bf(b[j]);
    }
    *(bf16x8*)(xb + i) = o;
}

// ---------------- prepass: packed int4 -> bf16 ----------------
__global__ __launch_bounds__(256)
void dequant_w_kernel(const int* __restrict__ wq, short* __restrict__ wb)
{
    const size_t i = ((size_t)blockIdx.x * 256 + threadIdx.x) * 4;
    const i32x4 v = *(const i32x4*)(wq + i);
    bf16x8 o;
    #pragma unroll
    for (int j = 0; j < 4; ++j) {
        const int q = (v[j] & 0xFF) ^ 0x88;
        o[2 * j]     = f2bf((float)((q & 15) - 8));
        o[2 * j + 1] = f2bf((float)(((q >> 4) & 15) - 8));
    }
    *(bf16x8*)(wb + i * 2) = o;
}

// ---------------- main GEMM: 256^2, 8 waves, counted-vmcnt 4-buffer pipeline ----------------
__global__ __launch_bounds__(512, 2)
void gemm256_kernel(const short* __restrict__ A,     // [8192][4096] bf16
                    const short* __restrict__ Bw,    // [11008][4096] bf16
                    const float* __restrict__ scale,
                    const float* __restrict__ bias,
                    float* __restrict__ out)
{
    __shared__ char lds[NBUF * BUF_BYTES];   // 128 KiB

    const int t    = threadIdx.x;
    const int lane = t & 63;
    const int wv   = t >> 6;          // 0..7
    const int wm   = wv >> 2;         // 0..1 -> M half
    const int wn   = wv & 3;          // 0..3 -> N quarter

    // bijective XCD chunk swizzle (nwg = 1376, %8 == 0)
    const int nbx = N_DIM / BN;                       // 43
    const int cpx = (nbx * (M_DIM / BM)) >> 3;        // 172
    const int bid = blockIdx.x;
    const int sid = (bid & 7) * cpx + (bid >> 3);
    const int by  = sid / nbx;
    const int bx  = sid - by * nbx;
    const int m0  = by * BM;
    const int n0  = bx * BN;

    // ---- staging: chunk c = wv*2+i covers rows [c*16, +16); lane -> row c*16+(l>>2), granule l&3
    // LDS dest is linear; SOURCE is pre-swizzled: g = g' ^ ((row>>1)&3)   (rule #21, m173)
    const int srow = lane >> 2;
    const int gp   = lane & 3;

    const short* aSrc[2];
    const short* bSrc[2];
    int aDst[2], bDst[2];
    #pragma unroll
    for (int i = 0; i < 2; ++i) {
        const int c   = wv * 2 + i;
        const int row = c * 16 + srow;
        const int g   = gp ^ ((row >> 1) & 3);
        aSrc[i] = A  + (size_t)(m0 + row) * K_DIM + g * 8;
        bSrc[i] = Bw + (size_t)(n0 + row) * K_DIM + g * 8;
        aDst[i] = c * 1024;
        bDst[i] = TILE_A_BYTES + c * 1024;
    }

#define STAGE(kt_) do {                                                                   \
    const int b_  = (kt_) & (NBUF - 1);                                                   \
    const int ko_ = (kt_) * BK;                                                           \
    _Pragma("unroll")                                                                     \
    for (int i_ = 0; i_ < 2; ++i_) {                                                      \
        __builtin_amdgcn_global_load_lds(                                                 \
            (const __attribute__((address_space(1))) unsigned int*)(aSrc[i_] + ko_),      \
            (__attribute__((address_space(3))) unsigned int*)(lds + b_ * BUF_BYTES + aDst[i_]), \
            16, 0, 0);                                                                    \
        __builtin_amdgcn_global_load_lds(                                                 \
            (const __attribute__((address_space(1))) unsigned int*)(bSrc[i_] + ko_),      \
            (__attribute__((address_space(3))) unsigned int*)(lds + b_ * BUF_BYTES + bDst[i_]), \
            16, 0, 0);                                                                    \
    }                                                                                     \
} while (0)

    // ---- fragment read offsets (swizzled reads; same involution as staging) ----
    const int lr = lane & 15;
    const int lk = lane >> 4;
    int aRd[8], bRd[4];
    #pragma unroll
    for (int mi = 0; mi < 8; ++mi) {
        const int row = wm * 128 + mi * 16 + lr;
        aRd[mi] = row * 64 + ((lk * 16) ^ (((row >> 1) & 3) << 4));
    }
    #pragma unroll
    for (int ni = 0; ni < 4; ++ni) {
        const int row = wn * 64 + ni * 16 + lr;
        bRd[ni] = TILE_A_BYTES + row * 64 + ((lk * 16) ^ (((row >> 1) & 3) << 4));
    }

    f32x4 acc[8][4];
    #pragma unroll
    for (int mi = 0; mi < 8; ++mi)
        #pragma unroll
        for (int ni = 0; ni < 4; ++ni)
            acc[mi][ni] = (f32x4){0.f, 0.f, 0.f, 0.f};

    // prologue: fill tiles 0..2 (buffers 0..2); wait tile 0 (12 issued, allow 8)
    STAGE(0); STAGE(1); STAGE(2);
    asm volatile("s_waitcnt vmcnt(8)" ::: "memory");
    __builtin_amdgcn_s_barrier();

    for (int kt = 0; kt < NT; ++kt) {
        const char* buf = lds + (kt & (NBUF - 1)) * BUF_BYTES;
        if (kt + 3 < NT) STAGE(kt + 3);   // buffer last read by group kt-1: sealed by barrier

        bf16x8 af[8], bfr[4];
        #pragma unroll
        for (int mi = 0; mi < 8; ++mi) af[mi] = *(const bf16x8*)(buf + aRd[mi]);
        #pragma unroll
        for (int ni = 0; ni < 4; ++ni) bfr[ni] = *(const bf16x8*)(buf + bRd[ni]);

        __builtin_amdgcn_s_setprio(1);
        #pragma unroll
        for (int mi = 0; mi < 8; ++mi)
            #pragma unroll
            for (int ni = 0; ni < 4; ++ni)
                acc[mi][ni] = __builtin_amdgcn_mfma_f32_16x16x32_bf16(
                    af[mi], bfr[ni], acc[mi][ni], 0, 0, 0);
        __builtin_amdgcn_s_setprio(0);

        // counted waits: ensure tile kt+1 landed; keep tiles kt+2, kt+3 in flight
        if (kt < NT - 3)       asm volatile("s_waitcnt vmcnt(8)" ::: "memory");
        else if (kt == NT - 3) asm volatile("s_waitcnt vmcnt(4)" ::: "memory");
        else if (kt == NT - 2) asm volatile("s_waitcnt vmcnt(0)" ::: "memory");
        if (kt < NT - 1) __builtin_amdgcn_s_barrier();
    }

    // ---- epilogue: out = acc * scale[n] + bias[n] ----
    // C/D layout: col = lane&15, row = (lane>>4)*4 + reg   (verified m89/m91, passing R1/R2)
    #pragma unroll
    for (int ni = 0; ni < 4; ++ni) {
        const int gn = n0 + wn * 64 + ni * 16 + lr;
        const float sc = scale[gn];
        const float bi = bias[gn];
        #pragma unroll
        for (int mi = 0; mi < 8; ++mi) {
            const int gm = m0 + wm * 128 + mi * 16 + lk * 4;
            const f32x4 v = acc[mi][ni];
            #pragma unroll
            for (int r = 0; r < 4; ++r)
                out[(size_t)(gm + r) * N_DIM + gn] = v[r] * sc + bi;
        }
    }
#undef STAGE
}

// ---------------- fallback: fused dequant GEMM (R1 kernel, known-good) ----------------
__device__ __forceinline__ int swz(int row, int kbyte) {
    return row * 128 + (kbyte ^ ((row & 7) << 4));
}

__global__ __launch_bounds__(256, 2)
void qlin_kernel(const float* __restrict__ x,
                 const int*   __restrict__ wq,
                 const float* __restrict__ scale,
                 const float* __restrict__ bias,
                 float* __restrict__ out)
{
    __shared__ short As[128 * 64];
    __shared__ short Bs[128 * 64];

    const int t  = threadIdx.x;
    const int n0 = blockIdx.x * 128;
    const int m0 = blockIdx.y * 128;

    const int sr = t >> 1;
    const int sh = t & 1;

    const float* ag = x  + (size_t)(m0 + sr) * K_DIM + sh * 32;
    const int*   bg = wq + (size_t)(n0 + sr) * KP    + sh * 16;

    const int lane = t & 63;
    const int wv   = t >> 6;
    const int wm   = wv >> 1;
    const int wn   = wv & 1;
    const int lr   = lane & 15;
    const int lk   = lane >> 4;

    f32x4 acc[4][4];
    #pragma unroll
    for (int i = 0; i < 4; ++i)
        #pragma unroll
        for (int j = 0; j < 4; ++j)
            acc[i][j] = (f32x4){0.f, 0.f, 0.f, 0.f};

    f32x4 ar[8];
    i32x4 br[4];

    #pragma unroll
    for (int i = 0; i < 8; ++i) ar[i] = *(const f32x4*)(ag + i * 4);
    #pragma unroll
    for (int i = 0; i < 4; ++i) br[i] = *(const i32x4*)(bg + i * 4);

    for (int kt = 0; kt < 64; ++kt) {
        #pragma unroll
        for (int c = 0; c < 4; ++c) {
            bf16x8 pa;
            #pragma unroll
            for (int j = 0; j < 8; ++j)
                pa[j] = f2bf(ar[c * 2 + (j >> 2)][j & 3]);
            *(bf16x8*)((char*)As + swz(sr, sh * 64 + c * 16)) = pa;

            bf16x8 pb;
            #pragma unroll
            for (int j = 0; j < 4; ++j) {
                const int q = br[c][j] ^ 0x88;
                const float flo = __builtin_bit_cast(float, 0x4B000000 | (q & 15))        - 8388616.0f;
                const float fhi = __builtin_bit_cast(float, 0x4B000000 | ((q >> 4) & 15)) - 8388616.0f;
                pb[2 * j]     = f2bf(flo);
                pb[2 * j + 1] = f2bf(fhi);
            }
            *(bf16x8*)((char*)Bs + swz(sr, sh * 64 + c * 16)) = pb;
        }
        __syncthreads();

        if (kt + 1 < 64) {
            const float* an = ag + (kt + 1) * 64;
            const int*   bn = bg + (kt + 1) * 32;
            #pragma unroll
            for (int i = 0; i < 8; ++i) ar[i] = *(const f32x4*)(an + i * 4);
            #pragma unroll
            for (int i = 0; i < 4; ++i) br[i] = *(const i32x4*)(bn + i * 4);
        }

        #pragma unroll
        for (int ks = 0; ks < 2; ++ks) {
            const int kb = ks * 64 + lk * 16;
            bf16x8 af[4], bfr[4];
            #pragma unroll
            for (int mi = 0; mi < 4; ++mi)
                af[mi] = *(const bf16x8*)((const char*)As + swz(wm * 64 + mi * 16 + lr, kb));
            #pragma unroll
            for (int ni = 0; ni < 4; ++ni)
                bfr[ni] = *(const bf16x8*)((const char*)Bs + swz(wn * 64 + ni * 16 + lr, kb));
            #pragma unroll
            for (int mi = 0; mi < 4; ++mi)
                #pragma unroll
                for (int ni = 0; ni < 4; ++ni)
                    acc[mi][ni] = __builtin_amdgcn_mfma_f32_16x16x32_bf16(
                        af[mi], bfr[ni], acc[mi][ni], 0, 0, 0);
        }
        __syncthreads();
    }

    #pragma unroll
    for (int ni = 0; ni < 4; ++ni) {
        const int gn = n0 + wn * 64 + ni * 16 + lr;
        const float sc = scale[gn];
        const float bi = bias[gn];
        #pragma unroll
        for (int mi = 0; mi < 4; ++mi) {
            const int gm = m0 + wm * 64 + mi * 16 + lk * 4;
            const f32x4 v = acc[mi][ni];
            #pragma unroll
            for (int r2 = 0; r2 < 4; ++r2)
                out[(size_t)(gm + r2) * N_DIM + gn] = v[r2] * sc + bi;
        }
    }
}

extern "C" void kernel_launch(void* const* d_in, const int* in_sizes, int n_in,
                              void* d_out, int out_size, void* d_ws, size_t ws_size,
                              hipStream_t stream)
{
    const float* x     = (const float*)d_in[0];
    const int*   wq    = (const int*)d_in[1];
    const float* scale = (const float*)d_in[2];
    const float* bias  = (const float*)d_in[3];
    float*       out   = (float*)d_out;

    if (ws_size >= WS_NEED) {
        short* xb = (short*)d_ws;
        short* wb = (short*)((char*)d_ws + A_WS_BYTES);
        cvt_x_kernel<<<16384, 256, 0, stream>>>(x, xb);
        dequant_w_kernel<<<22016, 256, 0, stream>>>(wq, wb);
        const int nwg = (N_DIM / BN) * (M_DIM / BM);   // 43*32 = 1376
        gemm256_kernel<<<nwg, 512, 0, stream>>>(xb, wb, scale, bias, out);
    } else {
        qlin_kernel<<<dim3(N_DIM / 128, M_DIM / 128), 256, 0, stream>>>(x, wq, scale, bias, out);
    }
}